// Round 3
// baseline (114.523 us; speedup 1.0000x reference)
//
#include <hip/hip_runtime.h>
#include <hip/hip_bf16.h>

// WaveletLinear fused:
//   y[b,o] = sum_i w[o,i] * (1 - s^2) * exp(-0.5 s^2),
//   s = (x[b,i] - t[o,i]) / (A_MIN + softplus(sr[o,i]) + EPS)
// Rework: u = K*s^2, K = 0.5*log2(e); e = exp2(-u); contrib = w*e - (w/K)*(u*e).
//
// R3: thread = 1 o x 4 b. Per i-step: one ds_read_b128 (params) + one
// ds_read_b128 (4 consecutive b from transposed x tile) feed 2 packed pairs.
// Param broadcasts built once per i, shared by both pairs. This quarters
// LDS instrs/elem vs R2 (the hidden limiter: LDS pipe ~37us at 2 b/thread).

#define WL_A_MIN 0.001f
#define WL_EPS   1e-8f

constexpr int WL_B = 512;
constexpr int WL_O = 1024;
constexpr int WL_I = 512;

constexpr int O_TILE = 16;
constexpr int B_TILE = 64;
constexpr int KC     = 64;

constexpr int PS = KC * 4 + 4;   // param row stride (floats); 260 % 4 == 0 (16B align)
constexpr int XS = B_TILE + 4;   // transposed-x row stride; 68 % 4 == 0, 68 % 32 = 4

// K = 0.5*log2(e); sqrt(K); 1/K; log2(e); ln(2)
#define WL_SQK  0.84932180553704583800f
#define WL_IK   1.38629436111989061883f
#define WL_L2E  1.44269504088896340736f
#define WL_LN2  0.69314718055994530942f

typedef float v2f __attribute__((ext_vector_type(2)));

__device__ __forceinline__ float fast_exp2(float a) {
#if __has_builtin(__builtin_amdgcn_exp2f)
    return __builtin_amdgcn_exp2f(a);
#else
    return exp2f(a);
#endif
}
__device__ __forceinline__ float fast_log2(float a) {
#if __has_builtin(__builtin_amdgcn_logf)
    return __builtin_amdgcn_logf(a);
#else
    return __log2f(a);
#endif
}
__device__ __forceinline__ float fast_rcp(float a) {
#if __has_builtin(__builtin_amdgcn_rcpf)
    return __builtin_amdgcn_rcpf(a);
#else
    return 1.0f / a;
#endif
}

// grid = (O/O_TILE=64, B/B_TILE=8) = 512 blocks, 2 blocks/CU, 8 waves/CU.
// blockIdx.x = o-tile so b-tiles sharing params co-locate on an XCD's L2.
__global__ __launch_bounds__(256, 2) void wl_fused(
    const float* __restrict__ x,
    const float* __restrict__ translation,
    const float* __restrict__ scale_raw,
    const float* __restrict__ weights,
    float* __restrict__ out)
{
    __shared__ float p_lds[O_TILE * PS];   // 16*260*4 = 16640 B
    __shared__ float x_lds[KC * XS];       // 64*68*4  = 17408 B

    const int tid    = threadIdx.x;
    const int ox     = tid & 15;           // o within tile
    const int bg     = tid >> 4;           // 0..15, group of 4 b
    const int o_base = blockIdx.x * O_TILE;
    const int b_base = blockIdx.y * B_TILE;

    v2f accA = {0.0f, 0.0f};               // b+0, b+1
    v2f accB = {0.0f, 0.0f};               // b+2, b+3

    for (int kc = 0; kc < WL_I; kc += KC) {
        // ---- stage params: 16 o x 64 i; 4 per thread; coalesced global ----
        #pragma unroll
        for (int k = 0; k < 4; ++k) {
            int lin = k * 256 + tid;               // 0..1023
            int o_l = lin >> 6;                    // 0..15
            int i_l = lin & 63;                    // 0..63
            int gi  = (o_base + o_l) * WL_I + kc + i_l;
            float t  = translation[gi];
            float sr = scale_raw[gi];
            float w  = weights[gi];
            // softplus via hw exp2/log2
            float ex    = fast_exp2(sr * WL_L2E);
            float sp    = fast_log2(1.0f + ex) * WL_LN2;
            float inv   = fast_rcp(WL_A_MIN + sp + WL_EPS);
            float inv_s = inv * WL_SQK;            // inv * sqrt(K)
            float4 pv = make_float4(-t * inv_s, inv_s, w, w * WL_IK);
            *reinterpret_cast<float4*>(&p_lds[o_l * PS + i_l * 4]) = pv;
        }
        // ---- stage x transposed: x_lds[i][b]; lane = b -> conflict-free writes
        {
            int b_r = tid & 63;                    // b row (lane-contiguous)
            int seg = tid >> 6;                    // 0..3 -> i = seg*16 .. +15
            const float* xg = &x[(b_base + b_r) * WL_I + kc + seg * 16];
            #pragma unroll
            for (int q = 0; q < 4; ++q) {
                float4 v = *reinterpret_cast<const float4*>(&xg[q * 4]);
                int i0 = seg * 16 + q * 4;
                x_lds[(i0 + 0) * XS + b_r] = v.x;
                x_lds[(i0 + 1) * XS + b_r] = v.y;
                x_lds[(i0 + 2) * XS + b_r] = v.z;
                x_lds[(i0 + 3) * XS + b_r] = v.w;
            }
        }
        __syncthreads();

        const float* pr = &p_lds[ox * PS];

        #pragma unroll 4
        for (int i = 0; i < KC; ++i) {
            float4 p  = *reinterpret_cast<const float4*>(&pr[i * 4]);
            float4 xq = *reinterpret_cast<const float4*>(&x_lds[i * XS + bg * 4]);
            v2f nti2 = {p.x, p.x};
            v2f inv2 = {p.y, p.y};
            v2f w2   = {p.z, p.z};
            v2f nk2  = {-p.w, -p.w};
            v2f xa = {xq.x, xq.y};
            v2f xb = {xq.z, xq.w};
            v2f sa = __builtin_elementwise_fma(xa, inv2, nti2);  // v_pk_fma_f32
            v2f sb = __builtin_elementwise_fma(xb, inv2, nti2);
            v2f ua = sa * sa;                                    // v_pk_mul_f32
            v2f ub = sb * sb;
            v2f ea = {fast_exp2(-ua.x), fast_exp2(-ua.y)};       // v_exp_f32 (neg mod)
            v2f eb = {fast_exp2(-ub.x), fast_exp2(-ub.y)};
            accA = __builtin_elementwise_fma(w2, ea, accA);      // += w*e
            accB = __builtin_elementwise_fma(w2, eb, accB);
            v2f uea = ua * ea;
            v2f ueb = ub * eb;
            accA = __builtin_elementwise_fma(nk2, uea, accA);    // -= (w/K)*u*e
            accB = __builtin_elementwise_fma(nk2, ueb, accB);
        }
        __syncthreads();
    }

    const int o = o_base + ox;
    const int b = b_base + bg * 4;
    out[(b + 0) * WL_O + o] = accA.x;
    out[(b + 1) * WL_O + o] = accA.y;
    out[(b + 2) * WL_O + o] = accB.x;
    out[(b + 3) * WL_O + o] = accB.y;
}

extern "C" void kernel_launch(void* const* d_in, const int* in_sizes, int n_in,
                              void* d_out, int out_size, void* d_ws, size_t ws_size,
                              hipStream_t stream) {
    const float* x           = (const float*)d_in[0];
    const float* translation = (const float*)d_in[1];
    const float* scale_raw   = (const float*)d_in[2];
    const float* weights     = (const float*)d_in[3];
    float*       out         = (float*)d_out;

    wl_fused<<<dim3(WL_O / O_TILE, WL_B / B_TILE), dim3(256), 0, stream>>>(
        x, translation, scale_raw, weights, out);
}